// Round 5
// baseline (1359.283 us; speedup 1.0000x reference)
//
#include <hip/hip_runtime.h>
#include <cmath>
#include <cstdint>

typedef __bf16 bf16_t;
typedef __bf16 bf16x8 __attribute__((ext_vector_type(8)));
typedef __bf16 bf16x4 __attribute__((ext_vector_type(4)));
typedef float  f32x4  __attribute__((ext_vector_type(4)));

#define DEPTH 6
#define DIM   768
#define HEADS 12
#define DH    64
#define MLPD  3072
#define SEQ   1024
#define BATCH 4
#define MTOT  (BATCH*SEQ)   /* 4096 rows */
#define QKVN  2304          /* 3*768 */

static __device__ __forceinline__ bf16x8 ld8(const bf16_t* p) {
    return *(const bf16x8*)p;
}

// async global->LDS, 16B per lane. LDS dest is wave-uniform base + lane*16.
// We permute *source* addresses per lane to build XOR-swizzled LDS layouts.
typedef const __attribute__((address_space(1))) unsigned int gas_u32;
typedef __attribute__((address_space(3))) unsigned int las_u32;
static __device__ __forceinline__ void gload16(const bf16_t* g, bf16_t* l) {
    __builtin_amdgcn_global_load_lds((gas_u32*)g, (las_u32*)l, 16, 0, 0);
}

// ---------------- fp32 [K][N] -> bf16 [N][K] transposed weight ----------------
__global__ __launch_bounds__(256) void tcvt_kernel(const float* __restrict__ in,
                                                   bf16_t* __restrict__ out,
                                                   int K, int N) {
    __shared__ float ts[32][33];
    int n0 = blockIdx.x * 32, k0 = blockIdx.y * 32;
    size_t base = (size_t)blockIdx.z * K * N;
    int tx = threadIdx.x & 31, ty = threadIdx.x >> 5;   // 32 x 8
    #pragma unroll
    for (int r = 0; r < 32; r += 8)
        ts[ty + r][tx] = in[base + (size_t)(k0 + ty + r) * N + n0 + tx];
    __syncthreads();
    #pragma unroll
    for (int r = 0; r < 32; r += 8)
        out[base + (size_t)(n0 + ty + r) * K + k0 + tx] = (bf16_t)ts[tx][ty + r];
}

// ------- fused: x += bias + sum(partials); write x and LN(x), float4 lanes ---
// 192 threads, one float4 column-group each. nslices==0: pure LN.
__global__ __launch_bounds__(192) void lnr_kernel(const float* __restrict__ xin,
                                                  float* __restrict__ xout,
                                                  const float* __restrict__ P,
                                                  int nslices,
                                                  const float* __restrict__ bias,
                                                  const float* __restrict__ w,
                                                  const float* __restrict__ b,
                                                  bf16_t* __restrict__ h,
                                                  int writeLN) {
    int row = blockIdx.x, t = threadIdx.x;
    size_t r4 = (size_t)row * 192 + t;
    float4 v = ((const float4*)xin)[r4];
    if (nslices) {
        float4 bi = ((const float4*)bias)[t];
        v.x += bi.x; v.y += bi.y; v.z += bi.z; v.w += bi.w;
        for (int s = 0; s < nslices; s++) {
            float4 pv = ((const float4*)P)[(size_t)s * MTOT * 192 + r4];
            v.x += pv.x; v.y += pv.y; v.z += pv.z; v.w += pv.w;
        }
        ((float4*)xout)[r4] = v;
    }
    float s = v.x + v.y + v.z + v.w;
    float q = v.x * v.x + v.y * v.y + v.z * v.z + v.w * v.w;
    #pragma unroll
    for (int off = 32; off > 0; off >>= 1) {
        s += __shfl_down(s, off);
        q += __shfl_down(q, off);
    }
    __shared__ float ss[3], sq[3], stat[2];
    if ((t & 63) == 0) { ss[t >> 6] = s; sq[t >> 6] = q; }
    __syncthreads();
    if (t == 0) {
        float S = ss[0] + ss[1] + ss[2];
        float Q = sq[0] + sq[1] + sq[2];
        float mean = S * (1.0f / DIM);
        float var  = Q * (1.0f / DIM) - mean * mean;
        stat[0] = mean;
        stat[1] = rsqrtf(var + 1e-5f);
    }
    __syncthreads();
    if (writeLN) {
        float mean = stat[0], rstd = stat[1];
        float4 wv4 = ((const float4*)w)[t];
        float4 bv4 = ((const float4*)b)[t];
        bf16x4 o;
        o[0] = (bf16_t)((v.x - mean) * rstd * wv4.x + bv4.x);
        o[1] = (bf16_t)((v.y - mean) * rstd * wv4.y + bv4.y);
        o[2] = (bf16_t)((v.z - mean) * rstd * wv4.z + bv4.z);
        o[3] = (bf16_t)((v.w - mean) * rstd * wv4.w + bv4.w);
        *(bf16x4*)&h[(size_t)row * DIM + t * 4] = o;
    }
}

// ---------------- bf16 MFMA GEMM body ----------------------------------------
// A: [M][K] bf16, Bt: [N][K] bf16. 128xBN tile, BK=32, 2-buf LDS.
// Per iter: __syncthreads (drains own DMA; buf[it&1] ready, other buf free)
// -> stage(it+1) async DMA overlaps compute(it) -> ds_read + MFMA.
// LDS layout: row-major [rows][32], chunk position = chunk ^ ((row>>1)&3)
// (2-way bank aliasing only).
// EPI 0: Cb = A@B; V-tiles (n0>=1536) store transposed into Vt  (QKV)
// EPI 1: Cb = gelu(A@B+bias)                                    (MLP1)
// EPI 2: Cf[slice] = A@B  (plain fp32 partial store, split-K)   (proj/MLP2)
template <int EPI, int BN>
static __device__ __forceinline__ void gemm_body(const bf16_t* __restrict__ A,
                                                 const bf16_t* __restrict__ Bt,
                                                 const float* __restrict__ bias,
                                                 bf16_t* __restrict__ Cb,
                                                 float* __restrict__ Cf,
                                                 bf16_t* __restrict__ Vt,
                                                 int N, int K, int klen) {
    constexpr int NJ = BN / 32;            // wave covers 64 x (16*NJ)
    __shared__ __align__(16) bf16_t As[2][128 * 32];
    __shared__ __align__(16) bf16_t Bs[2][BN * 32];
    int t = threadIdx.x;
    int m0 = blockIdx.y * 128, n0 = blockIdx.x * BN;
    int kz = blockIdx.z;
    int kbeg = kz * klen;
    int lane = t & 63, l16 = lane & 15, quad = lane >> 4;
    int wv = t >> 6, wm = wv >> 1, wn = wv & 1;
    f32x4 acc[4][NJ] = {};

    // staging: wave wv covers A rows wv*32..wv*32+31 (two 1KB instrs) and
    // B rows wv*32..+31 (BN=128, two instrs) or wv*16..+15 (BN=64, one).
    // lane ln -> row ln>>2 in group, LDS chunk-pos ln&3 holding global chunk
    // (ln&3)^((ln>>3)&3)  [= pos ^ ((row>>1)&3)].
    int sr = lane >> 2;
    int sc = ((lane & 3) ^ ((lane >> 3) & 3)) * 8;
    const bf16_t* gA0 = A  + (size_t)(m0 + wv * 32 + sr) * K + sc;
    const bf16_t* gA1 = gA0 + (size_t)16 * K;
    const bf16_t* gB0 = Bt + (size_t)(n0 + wv * (BN == 128 ? 32 : 16) + sr) * K + sc;
    const bf16_t* gB1 = gB0 + (size_t)16 * K;   // BN==128 only
    bf16_t* lA0 = &As[0][(wv * 32) * 32];
    bf16_t* lA1 = &As[0][(wv * 32 + 16) * 32];
    bf16_t* lB0 = &Bs[0][(wv * (BN == 128 ? 32 : 16)) * 32];
    bf16_t* lB1 = &Bs[0][(wv * 32 + 16) * 32];  // BN==128 only
    constexpr int bufA = 128 * 32;
    constexpr int bufB = BN * 32;

    auto stage = [&](int buf, int k0) {
        gload16(gA0 + k0, lA0 + buf * bufA);
        gload16(gA1 + k0, lA1 + buf * bufA);
        gload16(gB0 + k0, lB0 + buf * bufB);
        if constexpr (BN == 128) gload16(gB1 + k0, lB1 + buf * bufB);
    };

    int nIt = klen >> 5;
    stage(0, kbeg);
    int posA = (quad ^ ((l16 >> 1) & 3)) * 8;   // swizzled frag chunk (2-way)

    for (int it = 0; it < nIt; it++) {
        __syncthreads();   // drains own DMA; buf[it&1] ready, other buf free
        if (it + 1 < nIt) stage((it + 1) & 1, kbeg + (it + 1) * 32);
        const bf16_t* as = As[it & 1];
        const bf16_t* bs = Bs[it & 1];
        bf16x8 af[4], bfr[NJ];
        #pragma unroll
        for (int i = 0; i < 4; i++)
            af[i] = ld8(&as[(wm * 64 + i * 16 + l16) * 32 + posA]);
        #pragma unroll
        for (int j = 0; j < NJ; j++)
            bfr[j] = ld8(&bs[(wn * (16 * NJ) + j * 16 + l16) * 32 + posA]);
        #pragma unroll
        for (int i = 0; i < 4; i++)
            #pragma unroll
            for (int j = 0; j < NJ; j++)
                acc[i][j] = __builtin_amdgcn_mfma_f32_16x16x32_bf16(af[i], bfr[j], acc[i][j], 0, 0, 0);
    }

    if constexpr (EPI == 0) {
        if (n0 >= 1536) {
            // V tile: store transposed into Vt[b][h][d][n], 8B per store
            int b = m0 >> 10;
            #pragma unroll
            for (int i = 0; i < 4; i++) {
                int n = (m0 & 1023) + wm * 64 + i * 16 + quad * 4;
                #pragma unroll
                for (int j = 0; j < NJ; j++) {
                    int hc = n0 + wn * (16 * NJ) + j * 16 + l16 - 1536;
                    int hh = hc >> 6, d = hc & 63;
                    bf16x4 ov;
                    #pragma unroll
                    for (int r = 0; r < 4; r++) ov[r] = (bf16_t)acc[i][j][r];
                    *(bf16x4*)&Vt[(((size_t)b * HEADS + hh) * 64 + d) * SEQ + n] = ov;
                }
            }
            return;
        }
    }
    #pragma unroll
    for (int i = 0; i < 4; i++) {
        int grow = m0 + wm * 64 + i * 16 + quad * 4;
        #pragma unroll
        for (int j = 0; j < NJ; j++) {
            int gcol = n0 + wn * (16 * NJ) + j * 16 + l16;
            float bv = 0.0f;
            if constexpr (EPI == 1) bv = bias[gcol];
            #pragma unroll
            for (int r = 0; r < 4; r++) {
                size_t idx = (size_t)(grow + r) * N + gcol;
                float v = acc[i][j][r];
                if constexpr (EPI == 0) {
                    Cb[idx] = (bf16_t)v;
                } else if constexpr (EPI == 1) {
                    v += bv;
                    v = 0.5f * v * (1.0f + erff(v * 0.70710678118654752f));
                    Cb[idx] = (bf16_t)v;
                } else {
                    Cf[(size_t)kz * MTOT * N + idx] = v;   // plain partial store
                }
            }
        }
    }
}

// Named wrappers: one per GEMM shape so rocprof distinguishes them.
__global__ __launch_bounds__(256) void qkv_gemm(const bf16_t* __restrict__ A,
                                                const bf16_t* __restrict__ Bt,
                                                bf16_t* __restrict__ Cb,
                                                bf16_t* __restrict__ Vt) {
    gemm_body<0, 64>(A, Bt, nullptr, Cb, nullptr, Vt, QKVN, DIM, DIM);
}
__global__ __launch_bounds__(256) void proj_gemm(const bf16_t* __restrict__ A,
                                                 const bf16_t* __restrict__ Bt,
                                                 float* __restrict__ Cf) {
    gemm_body<2, 64>(A, Bt, nullptr, nullptr, Cf, nullptr, DIM, DIM, 384);
}
__global__ __launch_bounds__(256) void mlp1_gemm(const bf16_t* __restrict__ A,
                                                 const bf16_t* __restrict__ Bt,
                                                 const float* __restrict__ bias,
                                                 bf16_t* __restrict__ Cb) {
    gemm_body<1, 64>(A, Bt, bias, Cb, nullptr, nullptr, MLPD, DIM, DIM);
}
__global__ __launch_bounds__(256) void mlp2_gemm(const bf16_t* __restrict__ A,
                                                 const bf16_t* __restrict__ Bt,
                                                 float* __restrict__ Cf) {
    gemm_body<2, 128>(A, Bt, nullptr, nullptr, Cf, nullptr, DIM, MLPD, 768);
}

// ---------------- flash attention v4: swizzled dbuf K/V + prefetch ----------
// Block = (b, h, 64 queries); wave wv owns 16 queries over full key range.
// K/V tiles [64][64] XOR-swizzled (pos = chunk^(row&7), 2-way banks),
// double-buffered; per iter: barrier -> prefetch next -> compute.
// (r0 form: no setprio — waves are barrier-lockstepped, the regime where
// setprio is null-to-negative; r4's setprio build regressed.)
__global__ __launch_bounds__(256) void attn_kernel(const bf16_t* __restrict__ qkv,
                                                   const bf16_t* __restrict__ vt,
                                                   bf16_t* __restrict__ out) {
    int qt = blockIdx.x, h = blockIdx.y, b = blockIdx.z;
    int t = threadIdx.x;
    int wv = t >> 6, lane = t & 63, l16 = lane & 15, quad = lane >> 4;
    const float LOG2E = 1.44269504f;
    int qw0 = qt * 64 + wv * 16;

    __shared__ __align__(16) bf16_t Ks[2][64 * 64];
    __shared__ __align__(16) bf16_t Vs[2][64 * 64];
    __shared__ __align__(16) bf16_t Pa[4][16 * 72];
    bf16_t* P = Pa[wv];

    size_t bS = (size_t)b * SEQ;
    const bf16_t* qrow = qkv + (bS + qw0 + l16) * QKVN + h * 64;
    bf16x8 qf0 = ld8(qrow + quad * 8);
    bf16x8 qf1 = ld8(qrow + 32 + quad * 8);

    float m = -3e38f, l = 0.0f;
    f32x4 o[4] = {};

    const bf16_t* kbase = qkv + bS * QKVN + 768 + h * 64;
    const bf16_t* vbase = vt + ((size_t)(b * HEADS + h) * 64) * SEQ;

    // staging: wave wv handles K instrs {wv*2, wv*2+1} and V instrs {wv*2, wv*2+1}.
    // lane ln -> row ln>>3 in 8-row group, pos ln&7 holds chunk (ln&7)^(ln>>3).
    int ar = lane >> 3;
    int ac = ((lane & 7) ^ ar) * 8;
    int i0 = wv * 2, i1 = wv * 2 + 1;
    const bf16_t* gK0 = kbase + (size_t)(i0 * 8 + ar) * QKVN + ac;
    const bf16_t* gK1 = kbase + (size_t)(i1 * 8 + ar) * QKVN + ac;
    const bf16_t* gV0 = vbase + (size_t)(i0 * 8 + ar) * SEQ + ac;
    const bf16_t* gV1 = vbase + (size_t)(i1 * 8 + ar) * SEQ + ac;

    auto stage = [&](int buf, int kb) {
        gload16(gK0 + (size_t)kb * QKVN, &Ks[buf][i0 * 8 * 64]);
        gload16(gK1 + (size_t)kb * QKVN, &Ks[buf][i1 * 8 * 64]);
        gload16(gV0 + kb, &Vs[buf][i0 * 8 * 64]);
        gload16(gV1 + kb, &Vs[buf][i1 * 8 * 64]);
    };

    stage(0, 0);
    int p0 = (quad ^ (l16 & 7)) * 8;         // chunks 0..3 (swizzled)
    int p1 = ((quad + 4) ^ (l16 & 7)) * 8;   // chunks 4..7 (swizzled)

    for (int it = 0; it < SEQ / 64; it++) {
        __syncthreads();
        if (it + 1 < SEQ / 64) stage((it + 1) & 1, (it + 1) * 64);
        const bf16_t* ks = Ks[it & 1];
        const bf16_t* vs = Vs[it & 1];

        f32x4 s[4];
        #pragma unroll
        for (int tt = 0; tt < 4; tt++) {
            const bf16_t* kr = &ks[(tt * 16 + l16) * 64];
            f32x4 z = {};
            z = __builtin_amdgcn_mfma_f32_16x16x32_bf16(ld8(kr + p0), qf0, z, 0, 0, 0);
            z = __builtin_amdgcn_mfma_f32_16x16x32_bf16(ld8(kr + p1), qf1, z, 0, 0, 0);
            s[tt] = z;   // s[tt][r]: key=it*64+tt*16+quad*4+r, query=l16
        }
        float mx = -3e38f;
        #pragma unroll
        for (int tt = 0; tt < 4; tt++)
            #pragma unroll
            for (int r = 0; r < 4; r++) {
                s[tt][r] *= 0.125f;
                mx = fmaxf(mx, s[tt][r]);
            }
        mx = fmaxf(mx, __shfl_xor(mx, 16));
        mx = fmaxf(mx, __shfl_xor(mx, 32));
        float mn = fmaxf(m, mx);
        float alpha = exp2f((m - mn) * LOG2E);
        m = mn;
        float nb = mn * LOG2E;
        float rs = 0.0f;
        #pragma unroll
        for (int tt = 0; tt < 4; tt++) {
            bf16x4 pkt;
            #pragma unroll
            for (int r = 0; r < 4; r++) {
                float p = exp2f(fmaf(s[tt][r], LOG2E, -nb));
                rs += p;
                pkt[r] = (bf16_t)p;
            }
            *(bf16x4*)&P[l16 * 72 + tt * 16 + quad * 4] = pkt;
        }
        l = l * alpha + rs;   // quad-partial; reduced at end
        #pragma unroll
        for (int jt = 0; jt < 4; jt++) o[jt] *= alpha;
        asm volatile("s_waitcnt lgkmcnt(0)" ::: "memory");  // per-wave P visible
        bf16x8 pf0 = ld8(&P[l16 * 72 + quad * 8]);
        bf16x8 pf1 = ld8(&P[l16 * 72 + 32 + quad * 8]);
        #pragma unroll
        for (int jt = 0; jt < 4; jt++) {
            const bf16_t* vr = &vs[(jt * 16 + l16) * 64];
            o[jt] = __builtin_amdgcn_mfma_f32_16x16x32_bf16(ld8(vr + p0), pf0, o[jt], 0, 0, 0);
            o[jt] = __builtin_amdgcn_mfma_f32_16x16x32_bf16(ld8(vr + p1), pf1, o[jt], 0, 0, 0);
        }
    }

    l += __shfl_xor(l, 16);
    l += __shfl_xor(l, 32);
    float inv = 1.0f / l;
    bf16_t* orow = out + (bS + qw0 + l16) * DIM + h * 64;
    #pragma unroll
    for (int jt = 0; jt < 4; jt++) {
        bf16x4 ov;
        #pragma unroll
        for (int r = 0; r < 4; r++) ov[r] = (bf16_t)(o[jt][r] * inv);
        *(bf16x4*)&orow[jt * 16 + quad * 4] = ov;
    }
}

extern "C" void kernel_launch(void* const* d_in, const int* in_sizes, int n_in,
                              void* d_out, int out_size, void* d_ws, size_t ws_size,
                              hipStream_t stream) {
    const float* x     = (const float*)d_in[0];
    const float* ln1_w = (const float*)d_in[1];
    const float* ln1_b = (const float*)d_in[2];
    const float* w_qkv = (const float*)d_in[3];
    const float* w_o   = (const float*)d_in[4];
    const float* b_o   = (const float*)d_in[5];
    const float* ln2_w = (const float*)d_in[6];
    const float* ln2_b = (const float*)d_in[7];
    const float* w1    = (const float*)d_in[8];
    const float* b1    = (const float*)d_in[9];
    const float* w2    = (const float*)d_in[10];
    const float* b2    = (const float*)d_in[11];
    float* out = (float*)d_out;

    char* ws = (char*)d_ws;
    size_t off = 0;
    auto alloc = [&](size_t bytes) -> char* {
        char* p = ws + off;
        off += (bytes + 255) & ~(size_t)255;
        return p;
    };
    bf16_t* wqkv_t = (bf16_t*)alloc((size_t)DEPTH * DIM * QKVN * 2);
    bf16_t* wo_t   = (bf16_t*)alloc((size_t)DEPTH * DIM * DIM * 2);
    bf16_t* w1_t   = (bf16_t*)alloc((size_t)DEPTH * DIM * MLPD * 2);
    bf16_t* w2_t   = (bf16_t*)alloc((size_t)DEPTH * MLPD * DIM * 2);
    bf16_t* hbuf   = (bf16_t*)alloc((size_t)MTOT * DIM * 2);
    bf16_t* qkvb   = (bf16_t*)alloc((size_t)MTOT * QKVN * 2);   // also Pp slice 0/1
    bf16_t* vtb    = (bf16_t*)alloc((size_t)BATCH * HEADS * 64 * SEQ * 2);
    bf16_t* aob    = (bf16_t*)alloc((size_t)MTOT * DIM * 2);
    bf16_t* midb   = (bf16_t*)alloc((size_t)MTOT * MLPD * 2);
    float*  Pm     = (float*)alloc((size_t)4 * MTOT * DIM * 4); // MLP2 partials
    float*  Pp     = (float*)qkvb;  // proj partials alias dead qkvb+vtb region
    if (off > ws_size) return;

    tcvt_kernel<<<dim3(QKVN / 32, DIM / 32, DEPTH), 256, 0, stream>>>(w_qkv, wqkv_t, DIM, QKVN);
    tcvt_kernel<<<dim3(DIM / 32,  DIM / 32, DEPTH), 256, 0, stream>>>(w_o,   wo_t,   DIM, DIM);
    tcvt_kernel<<<dim3(MLPD / 32, DIM / 32, DEPTH), 256, 0, stream>>>(w1,    w1_t,   DIM, MLPD);
    tcvt_kernel<<<dim3(DIM / 32, MLPD / 32, DEPTH), 256, 0, stream>>>(w2,    w2_t,   MLPD, DIM);

    hipMemcpyAsync(out, x, (size_t)MTOT * DIM * 4, hipMemcpyDeviceToDevice, stream);

    // initial LN1 (layer 0)
    lnr_kernel<<<MTOT, 192, 0, stream>>>(out, out, nullptr, 0, nullptr,
                                         ln1_w, ln1_b, hbuf, 1);

    for (int L = 0; L < DEPTH; L++) {
        // QKV: BN=64 -> 1152 blocks (4.5/CU), 24KB LDS
        qkv_gemm<<<dim3(QKVN / 64, MTOT / 128, 1), 256, 0, stream>>>(
            hbuf, wqkv_t + (size_t)L * DIM * QKVN, qkvb, vtb);
        attn_kernel<<<dim3(SEQ / 64, HEADS, BATCH), 256, 0, stream>>>(qkvb, vtb, aob);
        // proj: BN=64, split-K=2 -> 768 blocks (3/CU, was 1.5)
        proj_gemm<<<dim3(DIM / 64, MTOT / 128, 2), 256, 0, stream>>>(
            aob, wo_t + (size_t)L * DIM * DIM, Pp);
        lnr_kernel<<<MTOT, 192, 0, stream>>>(out, out, Pp, 2, b_o + L * DIM,
                                             ln2_w + L * DIM, ln2_b + L * DIM, hbuf, 1);
        // MLP1: BN=64 -> 1536 blocks (6/CU); r1-proven <=49us vs 71 at BN=128
        mlp1_gemm<<<dim3(MLPD / 64, MTOT / 128, 1), 256, 0, stream>>>(
            hbuf, w1_t + (size_t)L * DIM * MLPD, b1 + L * MLPD, midb);
        // MLP2: BN=128 (r0-proven; BN=64 blew FETCH to 110MB in r1), split-K=4
        mlp2_gemm<<<dim3(DIM / 128, MTOT / 128, 4), 256, 0, stream>>>(
            midb, w2_t + (size_t)L * MLPD * DIM, Pm);
        if (L < DEPTH - 1) {
            lnr_kernel<<<MTOT, 192, 0, stream>>>(out, out, Pm, 4, b2 + L * DIM,
                                                 ln1_w + (L + 1) * DIM,
                                                 ln1_b + (L + 1) * DIM, hbuf, 1);
        } else {
            lnr_kernel<<<MTOT, 192, 0, stream>>>(out, out, Pm, 4, b2 + L * DIM,
                                                 ln1_w, ln1_b, hbuf, 0);
        }
    }
}

// Round 6
// 1339.704 us; speedup vs baseline: 1.0146x; 1.0146x over previous
//
#include <hip/hip_runtime.h>
#include <cmath>
#include <cstdint>

typedef __bf16 bf16_t;
typedef __bf16 bf16x8 __attribute__((ext_vector_type(8)));
typedef __bf16 bf16x4 __attribute__((ext_vector_type(4)));
typedef float  f32x4  __attribute__((ext_vector_type(4)));

#define DEPTH 6
#define DIM   768
#define HEADS 12
#define DH    64
#define MLPD  3072
#define SEQ   1024
#define BATCH 4
#define MTOT  (BATCH*SEQ)   /* 4096 rows */
#define QKVN  2304          /* 3*768 */

static __device__ __forceinline__ bf16x8 ld8(const bf16_t* p) {
    return *(const bf16x8*)p;
}

// async global->LDS, 16B per lane. LDS dest is wave-uniform base + lane*16.
// We permute *source* addresses per lane to build XOR-swizzled LDS layouts.
typedef const __attribute__((address_space(1))) unsigned int gas_u32;
typedef __attribute__((address_space(3))) unsigned int las_u32;
static __device__ __forceinline__ void gload16(const bf16_t* g, bf16_t* l) {
    __builtin_amdgcn_global_load_lds((gas_u32*)g, (las_u32*)l, 16, 0, 0);
}

// ---------------- fp32 [K][N] -> bf16 [N][K] transposed weight ----------------
__global__ __launch_bounds__(256) void tcvt_kernel(const float* __restrict__ in,
                                                   bf16_t* __restrict__ out,
                                                   int K, int N) {
    __shared__ float ts[32][33];
    int n0 = blockIdx.x * 32, k0 = blockIdx.y * 32;
    size_t base = (size_t)blockIdx.z * K * N;
    int tx = threadIdx.x & 31, ty = threadIdx.x >> 5;   // 32 x 8
    #pragma unroll
    for (int r = 0; r < 32; r += 8)
        ts[ty + r][tx] = in[base + (size_t)(k0 + ty + r) * N + n0 + tx];
    __syncthreads();
    #pragma unroll
    for (int r = 0; r < 32; r += 8)
        out[base + (size_t)(n0 + ty + r) * K + k0 + tx] = (bf16_t)ts[tx][ty + r];
}

// ------- fused: x += bias + sum(partials); write x and LN(x), float4 lanes ---
// 192 threads, one float4 column-group each. nslices==0: pure LN.
__global__ __launch_bounds__(192) void lnr_kernel(const float* __restrict__ xin,
                                                  float* __restrict__ xout,
                                                  const float* __restrict__ P,
                                                  int nslices,
                                                  const float* __restrict__ bias,
                                                  const float* __restrict__ w,
                                                  const float* __restrict__ b,
                                                  bf16_t* __restrict__ h,
                                                  int writeLN) {
    int row = blockIdx.x, t = threadIdx.x;
    size_t r4 = (size_t)row * 192 + t;
    float4 v = ((const float4*)xin)[r4];
    if (nslices) {
        float4 bi = ((const float4*)bias)[t];
        v.x += bi.x; v.y += bi.y; v.z += bi.z; v.w += bi.w;
        for (int s = 0; s < nslices; s++) {
            float4 pv = ((const float4*)P)[(size_t)s * MTOT * 192 + r4];
            v.x += pv.x; v.y += pv.y; v.z += pv.z; v.w += pv.w;
        }
        ((float4*)xout)[r4] = v;
    }
    float s = v.x + v.y + v.z + v.w;
    float q = v.x * v.x + v.y * v.y + v.z * v.z + v.w * v.w;
    #pragma unroll
    for (int off = 32; off > 0; off >>= 1) {
        s += __shfl_down(s, off);
        q += __shfl_down(q, off);
    }
    __shared__ float ss[3], sq[3], stat[2];
    if ((t & 63) == 0) { ss[t >> 6] = s; sq[t >> 6] = q; }
    __syncthreads();
    if (t == 0) {
        float S = ss[0] + ss[1] + ss[2];
        float Q = sq[0] + sq[1] + sq[2];
        float mean = S * (1.0f / DIM);
        float var  = Q * (1.0f / DIM) - mean * mean;
        stat[0] = mean;
        stat[1] = rsqrtf(var + 1e-5f);
    }
    __syncthreads();
    if (writeLN) {
        float mean = stat[0], rstd = stat[1];
        float4 wv4 = ((const float4*)w)[t];
        float4 bv4 = ((const float4*)b)[t];
        bf16x4 o;
        o[0] = (bf16_t)((v.x - mean) * rstd * wv4.x + bv4.x);
        o[1] = (bf16_t)((v.y - mean) * rstd * wv4.y + bv4.y);
        o[2] = (bf16_t)((v.z - mean) * rstd * wv4.z + bv4.z);
        o[3] = (bf16_t)((v.w - mean) * rstd * wv4.w + bv4.w);
        *(bf16x4*)&h[(size_t)row * DIM + t * 4] = o;
    }
}

// ---------------- bf16 MFMA GEMM: swizzled LDS + one-barrier prefetch --------
// A: [M][K] bf16, Bt: [N][K] bf16. 128xBN tile, BK=32, double-buffered LDS.
// Per iter: barrier (drains own DMA; buf[it&1] ready, other free) -> prefetch
// next tile (async DMA overlaps compute) -> ds_read + MFMA on current.
// LDS layout: row-major [rows][32], chunk position = chunk ^ ((row>>1)&3)
// (2-way bank aliasing only).
// EPI 0: Cb = A@B; V-tiles (n0>=1536) store transposed into Vt  (QKV)
// EPI 1: Cb = gelu(A@B+bias)                                    (MLP1)
// EPI 2: Cf[slice] = A@B  (plain fp32 partial store, split-K)   (proj/MLP2)
// MLP1 uses BN=64 (measured 49-53us vs 71us at BN=128, two contexts);
// identifiable in profiles via LDS_Block_Size=24576 (others=32768).
template <int EPI, int BN>
__global__ __launch_bounds__(256) void gemm_kernel(const bf16_t* __restrict__ A,
                                                   const bf16_t* __restrict__ Bt,
                                                   const float* __restrict__ bias,
                                                   bf16_t* __restrict__ Cb,
                                                   float* __restrict__ Cf,
                                                   bf16_t* __restrict__ Vt,
                                                   int N, int K, int klen) {
    constexpr int NJ = BN / 32;            // wave covers 64 x (16*NJ)
    __shared__ __align__(16) bf16_t As[2][128 * 32];
    __shared__ __align__(16) bf16_t Bs[2][BN * 32];
    int t = threadIdx.x;
    int m0 = blockIdx.y * 128, n0 = blockIdx.x * BN;
    int kz = blockIdx.z;
    int kbeg = kz * klen;
    int lane = t & 63, l16 = lane & 15, quad = lane >> 4;
    int wv = t >> 6, wm = wv >> 1, wn = wv & 1;
    f32x4 acc[4][NJ] = {};

    // staging: wave wv covers A rows wv*32..wv*32+31 (two 1KB instrs) and
    // B rows wv*32..+31 (BN=128, two instrs) or wv*16..+15 (BN=64, one).
    // lane ln -> row ln>>2 in group, LDS chunk-pos ln&3 holding global chunk
    // (ln&3)^((ln>>3)&3)  [= pos ^ ((row>>1)&3)].
    int sr = lane >> 2;
    int sc = ((lane & 3) ^ ((lane >> 3) & 3)) * 8;
    const bf16_t* gA0 = A  + (size_t)(m0 + wv * 32 + sr) * K + sc;
    const bf16_t* gA1 = gA0 + (size_t)16 * K;
    const bf16_t* gB0 = Bt + (size_t)(n0 + wv * (BN == 128 ? 32 : 16) + sr) * K + sc;
    const bf16_t* gB1 = gB0 + (size_t)16 * K;   // BN==128 only
    bf16_t* lA0 = &As[0][(wv * 32) * 32];
    bf16_t* lA1 = &As[0][(wv * 32 + 16) * 32];
    bf16_t* lB0 = &Bs[0][(wv * (BN == 128 ? 32 : 16)) * 32];
    bf16_t* lB1 = &Bs[0][(wv * 32 + 16) * 32];  // BN==128 only
    constexpr int bufA = 128 * 32;
    constexpr int bufB = BN * 32;

    auto stage = [&](int buf, int k0) {
        gload16(gA0 + k0, lA0 + buf * bufA);
        gload16(gA1 + k0, lA1 + buf * bufA);
        gload16(gB0 + k0, lB0 + buf * bufB);
        if constexpr (BN == 128) gload16(gB1 + k0, lB1 + buf * bufB);
    };

    int nIt = klen >> 5;
    stage(0, kbeg);
    int posA = (quad ^ ((l16 >> 1) & 3)) * 8;   // swizzled frag chunk (2-way)

    for (int it = 0; it < nIt; it++) {
        __syncthreads();   // drains all waves' DMA -> buf[it&1] ready; other buf free
        if (it + 1 < nIt) stage((it + 1) & 1, kbeg + (it + 1) * 32);
        const bf16_t* as = As[it & 1];
        const bf16_t* bs = Bs[it & 1];
        bf16x8 af[4], bfr[NJ];
        #pragma unroll
        for (int i = 0; i < 4; i++)
            af[i] = ld8(&as[(wm * 64 + i * 16 + l16) * 32 + posA]);
        #pragma unroll
        for (int j = 0; j < NJ; j++)
            bfr[j] = ld8(&bs[(wn * (16 * NJ) + j * 16 + l16) * 32 + posA]);
        #pragma unroll
        for (int i = 0; i < 4; i++)
            #pragma unroll
            for (int j = 0; j < NJ; j++)
                acc[i][j] = __builtin_amdgcn_mfma_f32_16x16x32_bf16(af[i], bfr[j], acc[i][j], 0, 0, 0);
    }

    if constexpr (EPI == 0) {
        if (n0 >= 1536) {
            // V tile: store transposed into Vt[b][h][d][n], 8B per store
            int b = m0 >> 10;
            #pragma unroll
            for (int i = 0; i < 4; i++) {
                int n = (m0 & 1023) + wm * 64 + i * 16 + quad * 4;
                #pragma unroll
                for (int j = 0; j < NJ; j++) {
                    int hc = n0 + wn * (16 * NJ) + j * 16 + l16 - 1536;
                    int hh = hc >> 6, d = hc & 63;
                    bf16x4 ov;
                    #pragma unroll
                    for (int r = 0; r < 4; r++) ov[r] = (bf16_t)acc[i][j][r];
                    *(bf16x4*)&Vt[(((size_t)b * HEADS + hh) * 64 + d) * SEQ + n] = ov;
                }
            }
            return;
        }
    }
    #pragma unroll
    for (int i = 0; i < 4; i++) {
        int grow = m0 + wm * 64 + i * 16 + quad * 4;
        #pragma unroll
        for (int j = 0; j < NJ; j++) {
            int gcol = n0 + wn * (16 * NJ) + j * 16 + l16;
            float bv = 0.0f;
            if constexpr (EPI == 1) bv = bias[gcol];
            #pragma unroll
            for (int r = 0; r < 4; r++) {
                size_t idx = (size_t)(grow + r) * N + gcol;
                float v = acc[i][j][r];
                if constexpr (EPI == 0) {
                    Cb[idx] = (bf16_t)v;
                } else if constexpr (EPI == 1) {
                    v += bv;
                    v = 0.5f * v * (1.0f + erff(v * 0.70710678118654752f));
                    Cb[idx] = (bf16_t)v;
                } else {
                    Cf[(size_t)kz * MTOT * N + idx] = v;   // plain partial store
                }
            }
        }
    }
}

// ---------------- flash attention v4: swizzled dbuf K/V + prefetch ----------
// Block = (b, h, 64 queries); wave wv owns 16 queries over full key range.
// K/V tiles [64][64] XOR-swizzled (pos = chunk^(row&7), 2-way banks),
// double-buffered; per iter: barrier -> prefetch next -> compute.
// (r0 form: no setprio.)
__global__ __launch_bounds__(256) void attn_kernel(const bf16_t* __restrict__ qkv,
                                                   const bf16_t* __restrict__ vt,
                                                   bf16_t* __restrict__ out) {
    int qt = blockIdx.x, h = blockIdx.y, b = blockIdx.z;
    int t = threadIdx.x;
    int wv = t >> 6, lane = t & 63, l16 = lane & 15, quad = lane >> 4;
    const float LOG2E = 1.44269504f;
    int qw0 = qt * 64 + wv * 16;

    __shared__ __align__(16) bf16_t Ks[2][64 * 64];
    __shared__ __align__(16) bf16_t Vs[2][64 * 64];
    __shared__ __align__(16) bf16_t Pa[4][16 * 72];
    bf16_t* P = Pa[wv];

    size_t bS = (size_t)b * SEQ;
    const bf16_t* qrow = qkv + (bS + qw0 + l16) * QKVN + h * 64;
    bf16x8 qf0 = ld8(qrow + quad * 8);
    bf16x8 qf1 = ld8(qrow + 32 + quad * 8);

    float m = -3e38f, l = 0.0f;
    f32x4 o[4] = {};

    const bf16_t* kbase = qkv + bS * QKVN + 768 + h * 64;
    const bf16_t* vbase = vt + ((size_t)(b * HEADS + h) * 64) * SEQ;

    // staging: wave wv handles K instrs {wv*2, wv*2+1} and V instrs {wv*2, wv*2+1}.
    // lane ln -> row ln>>3 in 8-row group, pos ln&7 holds chunk (ln&7)^(ln>>3).
    int ar = lane >> 3;
    int ac = ((lane & 7) ^ ar) * 8;
    int i0 = wv * 2, i1 = wv * 2 + 1;
    const bf16_t* gK0 = kbase + (size_t)(i0 * 8 + ar) * QKVN + ac;
    const bf16_t* gK1 = kbase + (size_t)(i1 * 8 + ar) * QKVN + ac;
    const bf16_t* gV0 = vbase + (size_t)(i0 * 8 + ar) * SEQ + ac;
    const bf16_t* gV1 = vbase + (size_t)(i1 * 8 + ar) * SEQ + ac;

    auto stage = [&](int buf, int kb) {
        gload16(gK0 + (size_t)kb * QKVN, &Ks[buf][i0 * 8 * 64]);
        gload16(gK1 + (size_t)kb * QKVN, &Ks[buf][i1 * 8 * 64]);
        gload16(gV0 + kb, &Vs[buf][i0 * 8 * 64]);
        gload16(gV1 + kb, &Vs[buf][i1 * 8 * 64]);
    };

    stage(0, 0);
    int p0 = (quad ^ (l16 & 7)) * 8;         // chunks 0..3 (swizzled)
    int p1 = ((quad + 4) ^ (l16 & 7)) * 8;   // chunks 4..7 (swizzled)

    for (int it = 0; it < SEQ / 64; it++) {
        __syncthreads();
        if (it + 1 < SEQ / 64) stage((it + 1) & 1, (it + 1) * 64);
        const bf16_t* ks = Ks[it & 1];
        const bf16_t* vs = Vs[it & 1];

        f32x4 s[4];
        #pragma unroll
        for (int tt = 0; tt < 4; tt++) {
            const bf16_t* kr = &ks[(tt * 16 + l16) * 64];
            f32x4 z = {};
            z = __builtin_amdgcn_mfma_f32_16x16x32_bf16(ld8(kr + p0), qf0, z, 0, 0, 0);
            z = __builtin_amdgcn_mfma_f32_16x16x32_bf16(ld8(kr + p1), qf1, z, 0, 0, 0);
            s[tt] = z;   // s[tt][r]: key=it*64+tt*16+quad*4+r, query=l16
        }
        float mx = -3e38f;
        #pragma unroll
        for (int tt = 0; tt < 4; tt++)
            #pragma unroll
            for (int r = 0; r < 4; r++) {
                s[tt][r] *= 0.125f;
                mx = fmaxf(mx, s[tt][r]);
            }
        mx = fmaxf(mx, __shfl_xor(mx, 16));
        mx = fmaxf(mx, __shfl_xor(mx, 32));
        float mn = fmaxf(m, mx);
        float alpha = exp2f((m - mn) * LOG2E);
        m = mn;
        float nb = mn * LOG2E;
        float rs = 0.0f;
        #pragma unroll
        for (int tt = 0; tt < 4; tt++) {
            bf16x4 pkt;
            #pragma unroll
            for (int r = 0; r < 4; r++) {
                float p = exp2f(fmaf(s[tt][r], LOG2E, -nb));
                rs += p;
                pkt[r] = (bf16_t)p;
            }
            *(bf16x4*)&P[l16 * 72 + tt * 16 + quad * 4] = pkt;
        }
        l = l * alpha + rs;   // quad-partial; reduced at end
        #pragma unroll
        for (int jt = 0; jt < 4; jt++) o[jt] *= alpha;
        asm volatile("s_waitcnt lgkmcnt(0)" ::: "memory");  // per-wave P visible
        bf16x8 pf0 = ld8(&P[l16 * 72 + quad * 8]);
        bf16x8 pf1 = ld8(&P[l16 * 72 + 32 + quad * 8]);
        #pragma unroll
        for (int jt = 0; jt < 4; jt++) {
            const bf16_t* vr = &vs[(jt * 16 + l16) * 64];
            o[jt] = __builtin_amdgcn_mfma_f32_16x16x32_bf16(ld8(vr + p0), pf0, o[jt], 0, 0, 0);
            o[jt] = __builtin_amdgcn_mfma_f32_16x16x32_bf16(ld8(vr + p1), pf1, o[jt], 0, 0, 0);
        }
    }

    l += __shfl_xor(l, 16);
    l += __shfl_xor(l, 32);
    float inv = 1.0f / l;
    bf16_t* orow = out + (bS + qw0 + l16) * DIM + h * 64;
    #pragma unroll
    for (int jt = 0; jt < 4; jt++) {
        bf16x4 ov;
        #pragma unroll
        for (int r = 0; r < 4; r++) ov[r] = (bf16_t)(o[jt][r] * inv);
        *(bf16x4*)&orow[jt * 16 + quad * 4] = ov;
    }
}

extern "C" void kernel_launch(void* const* d_in, const int* in_sizes, int n_in,
                              void* d_out, int out_size, void* d_ws, size_t ws_size,
                              hipStream_t stream) {
    const float* x     = (const float*)d_in[0];
    const float* ln1_w = (const float*)d_in[1];
    const float* ln1_b = (const float*)d_in[2];
    const float* w_qkv = (const float*)d_in[3];
    const float* w_o   = (const float*)d_in[4];
    const float* b_o   = (const float*)d_in[5];
    const float* ln2_w = (const float*)d_in[6];
    const float* ln2_b = (const float*)d_in[7];
    const float* w1    = (const float*)d_in[8];
    const float* b1    = (const float*)d_in[9];
    const float* w2    = (const float*)d_in[10];
    const float* b2    = (const float*)d_in[11];
    float* out = (float*)d_out;

    char* ws = (char*)d_ws;
    size_t off = 0;
    auto alloc = [&](size_t bytes) -> char* {
        char* p = ws + off;
        off += (bytes + 255) & ~(size_t)255;
        return p;
    };
    bf16_t* wqkv_t = (bf16_t*)alloc((size_t)DEPTH * DIM * QKVN * 2);
    bf16_t* wo_t   = (bf16_t*)alloc((size_t)DEPTH * DIM * DIM * 2);
    bf16_t* w1_t   = (bf16_t*)alloc((size_t)DEPTH * DIM * MLPD * 2);
    bf16_t* w2_t   = (bf16_t*)alloc((size_t)DEPTH * MLPD * DIM * 2);
    bf16_t* hbuf   = (bf16_t*)alloc((size_t)MTOT * DIM * 2);
    bf16_t* qkvb   = (bf16_t*)alloc((size_t)MTOT * QKVN * 2);   // also Pp slice 0/1
    bf16_t* vtb    = (bf16_t*)alloc((size_t)BATCH * HEADS * 64 * SEQ * 2);
    bf16_t* aob    = (bf16_t*)alloc((size_t)MTOT * DIM * 2);
    bf16_t* midb   = (bf16_t*)alloc((size_t)MTOT * MLPD * 2);
    float*  Pm     = (float*)alloc((size_t)4 * MTOT * DIM * 4); // MLP2 partials
    float*  Pp     = (float*)qkvb;  // proj partials alias dead qkvb+vtb region
    if (off > ws_size) return;

    tcvt_kernel<<<dim3(QKVN / 32, DIM / 32, DEPTH), 256, 0, stream>>>(w_qkv, wqkv_t, DIM, QKVN);
    tcvt_kernel<<<dim3(DIM / 32,  DIM / 32, DEPTH), 256, 0, stream>>>(w_o,   wo_t,   DIM, DIM);
    tcvt_kernel<<<dim3(MLPD / 32, DIM / 32, DEPTH), 256, 0, stream>>>(w1,    w1_t,   DIM, MLPD);
    tcvt_kernel<<<dim3(DIM / 32, MLPD / 32, DEPTH), 256, 0, stream>>>(w2,    w2_t,   MLPD, DIM);

    hipMemcpyAsync(out, x, (size_t)MTOT * DIM * 4, hipMemcpyDeviceToDevice, stream);

    // initial LN1 (layer 0)
    lnr_kernel<<<MTOT, 192, 0, stream>>>(out, out, nullptr, 0, nullptr,
                                         ln1_w, ln1_b, hbuf, 1);

    for (int L = 0; L < DEPTH; L++) {
        // QKV: r0 config (BN=128, 2-buf)
        gemm_kernel<0, 128><<<dim3(QKVN / 128, MTOT / 128, 1), 256, 0, stream>>>(
            hbuf, wqkv_t + (size_t)L * DIM * QKVN, nullptr, qkvb, nullptr, vtb,
            QKVN, DIM, DIM);
        attn_kernel<<<dim3(SEQ / 64, HEADS, BATCH), 256, 0, stream>>>(qkvb, vtb, aob);
        // proj: r0 config (BN=128, 2-buf, split-K=2)
        gemm_kernel<2, 128><<<dim3(DIM / 128, MTOT / 128, 2), 256, 0, stream>>>(
            aob, wo_t + (size_t)L * DIM * DIM, nullptr, nullptr, Pp, nullptr,
            DIM, DIM, 384);
        lnr_kernel<<<MTOT, 192, 0, stream>>>(out, out, Pp, 2, b_o + L * DIM,
                                             ln2_w + L * DIM, ln2_b + L * DIM, hbuf, 1);
        // MLP1: THE single change vs r0 -- BN=64 2-buf (measured 49-53us vs 71)
        gemm_kernel<1, 64><<<dim3(MLPD / 64, MTOT / 128, 1), 256, 0, stream>>>(
            hbuf, w1_t + (size_t)L * DIM * MLPD, b1 + L * MLPD, midb, nullptr, nullptr,
            MLPD, DIM, DIM);
        // MLP2: r0 config (BN=128, 2-buf, split-K=4)
        gemm_kernel<2, 128><<<dim3(DIM / 128, MTOT / 128, 4), 256, 0, stream>>>(
            midb, w2_t + (size_t)L * MLPD * DIM, nullptr, nullptr, Pm, nullptr,
            DIM, MLPD, 768);
        if (L < DEPTH - 1) {
            lnr_kernel<<<MTOT, 192, 0, stream>>>(out, out, Pm, 4, b2 + L * DIM,
                                                 ln1_w + (L + 1) * DIM,
                                                 ln1_b + (L + 1) * DIM, hbuf, 1);
        } else {
            lnr_kernel<<<MTOT, 192, 0, stream>>>(out, out, Pm, 4, b2 + L * DIM,
                                                 ln1_w, ln1_b, hbuf, 0);
        }
    }
}

// Round 7
// 1283.364 us; speedup vs baseline: 1.0592x; 1.0439x over previous
//
#include <hip/hip_runtime.h>
#include <cmath>
#include <cstdint>

typedef __bf16 bf16_t;
typedef __bf16 bf16x8 __attribute__((ext_vector_type(8)));
typedef __bf16 bf16x4 __attribute__((ext_vector_type(4)));
typedef float  f32x4  __attribute__((ext_vector_type(4)));

#define DEPTH 6
#define DIM   768
#define HEADS 12
#define DH    64
#define MLPD  3072
#define SEQ   1024
#define BATCH 4
#define MTOT  (BATCH*SEQ)   /* 4096 rows */
#define QKVN  2304          /* 3*768 */

static __device__ __forceinline__ bf16x8 ld8(const bf16_t* p) {
    return *(const bf16x8*)p;
}

// async global->LDS, 16B per lane. LDS dest is wave-uniform base + lane*16.
// We permute *source* addresses per lane to build XOR-swizzled LDS layouts.
typedef const __attribute__((address_space(1))) unsigned int gas_u32;
typedef __attribute__((address_space(3))) unsigned int las_u32;
static __device__ __forceinline__ void gload16(const bf16_t* g, bf16_t* l) {
    __builtin_amdgcn_global_load_lds((gas_u32*)g, (las_u32*)l, 16, 0, 0);
}

// ---------------- fp32 [K][N] -> bf16 [N][K] transposed weight ----------------
__global__ __launch_bounds__(256) void tcvt_kernel(const float* __restrict__ in,
                                                   bf16_t* __restrict__ out,
                                                   int K, int N) {
    __shared__ float ts[32][33];
    int n0 = blockIdx.x * 32, k0 = blockIdx.y * 32;
    size_t base = (size_t)blockIdx.z * K * N;
    int tx = threadIdx.x & 31, ty = threadIdx.x >> 5;   // 32 x 8
    #pragma unroll
    for (int r = 0; r < 32; r += 8)
        ts[ty + r][tx] = in[base + (size_t)(k0 + ty + r) * N + n0 + tx];
    __syncthreads();
    #pragma unroll
    for (int r = 0; r < 32; r += 8)
        out[base + (size_t)(n0 + ty + r) * K + k0 + tx] = (bf16_t)ts[tx][ty + r];
}

// ------- fused: x += bias + sum(partials); write x and LN(x), float4 lanes ---
// 192 threads, one float4 column-group each. nslices==0: pure LN.
// (No swizzle here: streaming rows, zero inter-block reuse -- T1 null regime.)
__global__ __launch_bounds__(192) void lnr_kernel(const float* __restrict__ xin,
                                                  float* __restrict__ xout,
                                                  const float* __restrict__ P,
                                                  int nslices,
                                                  const float* __restrict__ bias,
                                                  const float* __restrict__ w,
                                                  const float* __restrict__ b,
                                                  bf16_t* __restrict__ h,
                                                  int writeLN) {
    int row = blockIdx.x, t = threadIdx.x;
    size_t r4 = (size_t)row * 192 + t;
    float4 v = ((const float4*)xin)[r4];
    if (nslices) {
        float4 bi = ((const float4*)bias)[t];
        v.x += bi.x; v.y += bi.y; v.z += bi.z; v.w += bi.w;
        for (int s = 0; s < nslices; s++) {
            float4 pv = ((const float4*)P)[(size_t)s * MTOT * 192 + r4];
            v.x += pv.x; v.y += pv.y; v.z += pv.z; v.w += pv.w;
        }
        ((float4*)xout)[r4] = v;
    }
    float s = v.x + v.y + v.z + v.w;
    float q = v.x * v.x + v.y * v.y + v.z * v.z + v.w * v.w;
    #pragma unroll
    for (int off = 32; off > 0; off >>= 1) {
        s += __shfl_down(s, off);
        q += __shfl_down(q, off);
    }
    __shared__ float ss[3], sq[3], stat[2];
    if ((t & 63) == 0) { ss[t >> 6] = s; sq[t >> 6] = q; }
    __syncthreads();
    if (t == 0) {
        float S = ss[0] + ss[1] + ss[2];
        float Q = sq[0] + sq[1] + sq[2];
        float mean = S * (1.0f / DIM);
        float var  = Q * (1.0f / DIM) - mean * mean;
        stat[0] = mean;
        stat[1] = rsqrtf(var + 1e-5f);
    }
    __syncthreads();
    if (writeLN) {
        float mean = stat[0], rstd = stat[1];
        float4 wv4 = ((const float4*)w)[t];
        float4 bv4 = ((const float4*)b)[t];
        bf16x4 o;
        o[0] = (bf16_t)((v.x - mean) * rstd * wv4.x + bv4.x);
        o[1] = (bf16_t)((v.y - mean) * rstd * wv4.y + bv4.y);
        o[2] = (bf16_t)((v.z - mean) * rstd * wv4.z + bv4.z);
        o[3] = (bf16_t)((v.w - mean) * rstd * wv4.w + bv4.w);
        *(bf16x4*)&h[(size_t)row * DIM + t * 4] = o;
    }
}

// ---------------- bf16 MFMA GEMM: swizzled LDS + one-barrier prefetch --------
// A: [M][K] bf16, Bt: [N][K] bf16. 128xBN tile, BK=32, double-buffered LDS.
// XCD-locality swizzle (NEW this round): remap (bx,by) so that all n-blocks
// sharing an A-panel (same by) have flat%8 == by%8 -> land on ONE XCD under
// round-robin dispatch. A-panel then lives in that XCD's L2 (fetched once);
// per-iter A-loads become L2 hits (~200cy) instead of cross-XCD misses
// (~450-900cy). Bijective: requires gridDim.y % 8 == 0 (all shapes: NY=32).
// Theory: MLP1 T_iter ~960cy at 15% MfmaUtil = un-hidden memory latency;
// prefetch depth can't cover it (unstalled iter ~200cy << miss ~900cy).
// LDS layout: row-major [rows][32], chunk position = chunk ^ ((row>>1)&3).
// EPI 0: Cb = A@B; V-tiles (n0>=1536) store transposed into Vt  (QKV)
// EPI 1: Cb = gelu(A@B+bias)                                    (MLP1)
// EPI 2: Cf[slice] = A@B  (plain fp32 partial store, split-K)   (proj/MLP2)
template <int EPI, int BN>
__global__ __launch_bounds__(256) void gemm_kernel(const bf16_t* __restrict__ A,
                                                   const bf16_t* __restrict__ Bt,
                                                   const float* __restrict__ bias,
                                                   bf16_t* __restrict__ Cb,
                                                   float* __restrict__ Cf,
                                                   bf16_t* __restrict__ Vt,
                                                   int N, int K, int klen) {
    constexpr int NJ = BN / 32;            // wave covers 64 x (16*NJ)
    __shared__ __align__(16) bf16_t As[2][128 * 32];
    __shared__ __align__(16) bf16_t Bs[2][BN * 32];
    int t = threadIdx.x;
    // XCD-locality remap: xcd := flat%8 == by%8
    int NX = gridDim.x;
    int flat = blockIdx.y * NX + blockIdx.x;
    int jj = flat >> 3;
    int bxs = jj % NX;
    int bys = (flat & 7) + ((jj / NX) << 3);
    int m0 = bys * 128, n0 = bxs * BN;
    int kz = blockIdx.z;
    int kbeg = kz * klen;
    int lane = t & 63, l16 = lane & 15, quad = lane >> 4;
    int wv = t >> 6, wm = wv >> 1, wn = wv & 1;
    f32x4 acc[4][NJ] = {};

    // staging: wave wv covers A rows wv*32..wv*32+31 (two 1KB instrs) and
    // B rows wv*32..+31 (BN=128, two instrs) or wv*16..+15 (BN=64, one).
    // lane ln -> row ln>>2 in group, LDS chunk-pos ln&3 holding global chunk
    // (ln&3)^((ln>>3)&3)  [= pos ^ ((row>>1)&3)].
    int sr = lane >> 2;
    int sc = ((lane & 3) ^ ((lane >> 3) & 3)) * 8;
    const bf16_t* gA0 = A  + (size_t)(m0 + wv * 32 + sr) * K + sc;
    const bf16_t* gA1 = gA0 + (size_t)16 * K;
    const bf16_t* gB0 = Bt + (size_t)(n0 + wv * (BN == 128 ? 32 : 16) + sr) * K + sc;
    const bf16_t* gB1 = gB0 + (size_t)16 * K;   // BN==128 only
    bf16_t* lA0 = &As[0][(wv * 32) * 32];
    bf16_t* lA1 = &As[0][(wv * 32 + 16) * 32];
    bf16_t* lB0 = &Bs[0][(wv * (BN == 128 ? 32 : 16)) * 32];
    bf16_t* lB1 = &Bs[0][(wv * 32 + 16) * 32];  // BN==128 only
    constexpr int bufA = 128 * 32;
    constexpr int bufB = BN * 32;

    auto stage = [&](int buf, int k0) {
        gload16(gA0 + k0, lA0 + buf * bufA);
        gload16(gA1 + k0, lA1 + buf * bufA);
        gload16(gB0 + k0, lB0 + buf * bufB);
        if constexpr (BN == 128) gload16(gB1 + k0, lB1 + buf * bufB);
    };

    int nIt = klen >> 5;
    stage(0, kbeg);
    int posA = (quad ^ ((l16 >> 1) & 3)) * 8;   // swizzled frag chunk (2-way)

    for (int it = 0; it < nIt; it++) {
        __syncthreads();   // drains all waves' DMA -> buf[it&1] ready; other buf free
        if (it + 1 < nIt) stage((it + 1) & 1, kbeg + (it + 1) * 32);
        const bf16_t* as = As[it & 1];
        const bf16_t* bs = Bs[it & 1];
        bf16x8 af[4], bfr[NJ];
        #pragma unroll
        for (int i = 0; i < 4; i++)
            af[i] = ld8(&as[(wm * 64 + i * 16 + l16) * 32 + posA]);
        #pragma unroll
        for (int j = 0; j < NJ; j++)
            bfr[j] = ld8(&bs[(wn * (16 * NJ) + j * 16 + l16) * 32 + posA]);
        #pragma unroll
        for (int i = 0; i < 4; i++)
            #pragma unroll
            for (int j = 0; j < NJ; j++)
                acc[i][j] = __builtin_amdgcn_mfma_f32_16x16x32_bf16(af[i], bfr[j], acc[i][j], 0, 0, 0);
    }

    if constexpr (EPI == 0) {
        if (n0 >= 1536) {
            // V tile: store transposed into Vt[b][h][d][n], 8B per store
            int b = m0 >> 10;
            #pragma unroll
            for (int i = 0; i < 4; i++) {
                int n = (m0 & 1023) + wm * 64 + i * 16 + quad * 4;
                #pragma unroll
                for (int j = 0; j < NJ; j++) {
                    int hc = n0 + wn * (16 * NJ) + j * 16 + l16 - 1536;
                    int hh = hc >> 6, d = hc & 63;
                    bf16x4 ov;
                    #pragma unroll
                    for (int r = 0; r < 4; r++) ov[r] = (bf16_t)acc[i][j][r];
                    *(bf16x4*)&Vt[(((size_t)b * HEADS + hh) * 64 + d) * SEQ + n] = ov;
                }
            }
            return;
        }
    }
    #pragma unroll
    for (int i = 0; i < 4; i++) {
        int grow = m0 + wm * 64 + i * 16 + quad * 4;
        #pragma unroll
        for (int j = 0; j < NJ; j++) {
            int gcol = n0 + wn * (16 * NJ) + j * 16 + l16;
            float bv = 0.0f;
            if constexpr (EPI == 1) bv = bias[gcol];
            #pragma unroll
            for (int r = 0; r < 4; r++) {
                size_t idx = (size_t)(grow + r) * N + gcol;
                float v = acc[i][j][r];
                if constexpr (EPI == 0) {
                    Cb[idx] = (bf16_t)v;
                } else if constexpr (EPI == 1) {
                    v += bv;
                    v = 0.5f * v * (1.0f + erff(v * 0.70710678118654752f));
                    Cb[idx] = (bf16_t)v;
                } else {
                    Cf[(size_t)kz * MTOT * N + idx] = v;   // plain partial store
                }
            }
        }
    }
}

// ---------------- flash attention v4: swizzled dbuf K/V + prefetch ----------
// Block = (b, h, 64 queries); wave wv owns 16 queries over full key range.
// K/V tiles [64][64] XOR-swizzled (pos = chunk^(row&7), 2-way banks),
// double-buffered; per iter: barrier -> prefetch next -> compute.
// XCD-locality swizzle (NEW): the 16 q-tiles of one (b,h) share 256KB of
// K/V; pin them to one XCD (flat%8) so K/V is L2-resident after first tile.
__global__ __launch_bounds__(256) void attn_kernel(const bf16_t* __restrict__ qkv,
                                                   const bf16_t* __restrict__ vt,
                                                   bf16_t* __restrict__ out) {
    int flat = (blockIdx.z * gridDim.y + blockIdx.y) * gridDim.x + blockIdx.x;
    int jj = flat >> 3;
    int qt = jj & 15;                       // gridDim.x == 16
    int bh = (flat & 7) + ((jj >> 4) << 3); // in [0, 48)
    int h = bh % HEADS, b = bh / HEADS;
    int t = threadIdx.x;
    int wv = t >> 6, lane = t & 63, l16 = lane & 15, quad = lane >> 4;
    const float LOG2E = 1.44269504f;
    int qw0 = qt * 64 + wv * 16;

    __shared__ __align__(16) bf16_t Ks[2][64 * 64];
    __shared__ __align__(16) bf16_t Vs[2][64 * 64];
    __shared__ __align__(16) bf16_t Pa[4][16 * 72];
    bf16_t* P = Pa[wv];

    size_t bS = (size_t)b * SEQ;
    const bf16_t* qrow = qkv + (bS + qw0 + l16) * QKVN + h * 64;
    bf16x8 qf0 = ld8(qrow + quad * 8);
    bf16x8 qf1 = ld8(qrow + 32 + quad * 8);

    float m = -3e38f, l = 0.0f;
    f32x4 o[4] = {};

    const bf16_t* kbase = qkv + bS * QKVN + 768 + h * 64;
    const bf16_t* vbase = vt + ((size_t)(b * HEADS + h) * 64) * SEQ;

    // staging: wave wv handles K instrs {wv*2, wv*2+1} and V instrs {wv*2, wv*2+1}.
    // lane ln -> row ln>>3 in 8-row group, pos ln&7 holds chunk (ln&7)^(ln>>3).
    int ar = lane >> 3;
    int ac = ((lane & 7) ^ ar) * 8;
    int i0 = wv * 2, i1 = wv * 2 + 1;
    const bf16_t* gK0 = kbase + (size_t)(i0 * 8 + ar) * QKVN + ac;
    const bf16_t* gK1 = kbase + (size_t)(i1 * 8 + ar) * QKVN + ac;
    const bf16_t* gV0 = vbase + (size_t)(i0 * 8 + ar) * SEQ + ac;
    const bf16_t* gV1 = vbase + (size_t)(i1 * 8 + ar) * SEQ + ac;

    auto stage = [&](int buf, int kb) {
        gload16(gK0 + (size_t)kb * QKVN, &Ks[buf][i0 * 8 * 64]);
        gload16(gK1 + (size_t)kb * QKVN, &Ks[buf][i1 * 8 * 64]);
        gload16(gV0 + kb, &Vs[buf][i0 * 8 * 64]);
        gload16(gV1 + kb, &Vs[buf][i1 * 8 * 64]);
    };

    stage(0, 0);
    int p0 = (quad ^ (l16 & 7)) * 8;         // chunks 0..3 (swizzled)
    int p1 = ((quad + 4) ^ (l16 & 7)) * 8;   // chunks 4..7 (swizzled)

    for (int it = 0; it < SEQ / 64; it++) {
        __syncthreads();
        if (it + 1 < SEQ / 64) stage((it + 1) & 1, (it + 1) * 64);
        const bf16_t* ks = Ks[it & 1];
        const bf16_t* vs = Vs[it & 1];

        f32x4 s[4];
        #pragma unroll
        for (int tt = 0; tt < 4; tt++) {
            const bf16_t* kr = &ks[(tt * 16 + l16) * 64];
            f32x4 z = {};
            z = __builtin_amdgcn_mfma_f32_16x16x32_bf16(ld8(kr + p0), qf0, z, 0, 0, 0);
            z = __builtin_amdgcn_mfma_f32_16x16x32_bf16(ld8(kr + p1), qf1, z, 0, 0, 0);
            s[tt] = z;   // s[tt][r]: key=it*64+tt*16+quad*4+r, query=l16
        }
        float mx = -3e38f;
        #pragma unroll
        for (int tt = 0; tt < 4; tt++)
            #pragma unroll
            for (int r = 0; r < 4; r++) {
                s[tt][r] *= 0.125f;
                mx = fmaxf(mx, s[tt][r]);
            }
        mx = fmaxf(mx, __shfl_xor(mx, 16));
        mx = fmaxf(mx, __shfl_xor(mx, 32));
        float mn = fmaxf(m, mx);
        float alpha = exp2f((m - mn) * LOG2E);
        m = mn;
        float nb = mn * LOG2E;
        float rs = 0.0f;
        #pragma unroll
        for (int tt = 0; tt < 4; tt++) {
            bf16x4 pkt;
            #pragma unroll
            for (int r = 0; r < 4; r++) {
                float p = exp2f(fmaf(s[tt][r], LOG2E, -nb));
                rs += p;
                pkt[r] = (bf16_t)p;
            }
            *(bf16x4*)&P[l16 * 72 + tt * 16 + quad * 4] = pkt;
        }
        l = l * alpha + rs;   // quad-partial; reduced at end
        #pragma unroll
        for (int jt = 0; jt < 4; jt++) o[jt] *= alpha;
        asm volatile("s_waitcnt lgkmcnt(0)" ::: "memory");  // per-wave P visible
        bf16x8 pf0 = ld8(&P[l16 * 72 + quad * 8]);
        bf16x8 pf1 = ld8(&P[l16 * 72 + 32 + quad * 8]);
        #pragma unroll
        for (int jt = 0; jt < 4; jt++) {
            const bf16_t* vr = &vs[(jt * 16 + l16) * 64];
            o[jt] = __builtin_amdgcn_mfma_f32_16x16x32_bf16(ld8(vr + p0), pf0, o[jt], 0, 0, 0);
            o[jt] = __builtin_amdgcn_mfma_f32_16x16x32_bf16(ld8(vr + p1), pf1, o[jt], 0, 0, 0);
        }
    }

    l += __shfl_xor(l, 16);
    l += __shfl_xor(l, 32);
    float inv = 1.0f / l;
    bf16_t* orow = out + (bS + qw0 + l16) * DIM + h * 64;
    #pragma unroll
    for (int jt = 0; jt < 4; jt++) {
        bf16x4 ov;
        #pragma unroll
        for (int r = 0; r < 4; r++) ov[r] = (bf16_t)(o[jt][r] * inv);
        *(bf16x4*)&orow[jt * 16 + quad * 4] = ov;
    }
}

extern "C" void kernel_launch(void* const* d_in, const int* in_sizes, int n_in,
                              void* d_out, int out_size, void* d_ws, size_t ws_size,
                              hipStream_t stream) {
    const float* x     = (const float*)d_in[0];
    const float* ln1_w = (const float*)d_in[1];
    const float* ln1_b = (const float*)d_in[2];
    const float* w_qkv = (const float*)d_in[3];
    const float* w_o   = (const float*)d_in[4];
    const float* b_o   = (const float*)d_in[5];
    const float* ln2_w = (const float*)d_in[6];
    const float* ln2_b = (const float*)d_in[7];
    const float* w1    = (const float*)d_in[8];
    const float* b1    = (const float*)d_in[9];
    const float* w2    = (const float*)d_in[10];
    const float* b2    = (const float*)d_in[11];
    float* out = (float*)d_out;

    char* ws = (char*)d_ws;
    size_t off = 0;
    auto alloc = [&](size_t bytes) -> char* {
        char* p = ws + off;
        off += (bytes + 255) & ~(size_t)255;
        return p;
    };
    bf16_t* wqkv_t = (bf16_t*)alloc((size_t)DEPTH * DIM * QKVN * 2);
    bf16_t* wo_t   = (bf16_t*)alloc((size_t)DEPTH * DIM * DIM * 2);
    bf16_t* w1_t   = (bf16_t*)alloc((size_t)DEPTH * DIM * MLPD * 2);
    bf16_t* w2_t   = (bf16_t*)alloc((size_t)DEPTH * MLPD * DIM * 2);
    bf16_t* hbuf   = (bf16_t*)alloc((size_t)MTOT * DIM * 2);
    bf16_t* qkvb   = (bf16_t*)alloc((size_t)MTOT * QKVN * 2);   // also Pp slice 0/1
    bf16_t* vtb    = (bf16_t*)alloc((size_t)BATCH * HEADS * 64 * SEQ * 2);
    bf16_t* aob    = (bf16_t*)alloc((size_t)MTOT * DIM * 2);
    bf16_t* midb   = (bf16_t*)alloc((size_t)MTOT * MLPD * 2);
    float*  Pm     = (float*)alloc((size_t)4 * MTOT * DIM * 4); // MLP2 partials
    float*  Pp     = (float*)qkvb;  // proj partials alias dead qkvb+vtb region
    if (off > ws_size) return;

    tcvt_kernel<<<dim3(QKVN / 32, DIM / 32, DEPTH), 256, 0, stream>>>(w_qkv, wqkv_t, DIM, QKVN);
    tcvt_kernel<<<dim3(DIM / 32,  DIM / 32, DEPTH), 256, 0, stream>>>(w_o,   wo_t,   DIM, DIM);
    tcvt_kernel<<<dim3(MLPD / 32, DIM / 32, DEPTH), 256, 0, stream>>>(w1,    w1_t,   DIM, MLPD);
    tcvt_kernel<<<dim3(DIM / 32, MLPD / 32, DEPTH), 256, 0, stream>>>(w2,    w2_t,   MLPD, DIM);

    hipMemcpyAsync(out, x, (size_t)MTOT * DIM * 4, hipMemcpyDeviceToDevice, stream);

    // initial LN1 (layer 0)
    lnr_kernel<<<MTOT, 192, 0, stream>>>(out, out, nullptr, 0, nullptr,
                                         ln1_w, ln1_b, hbuf, 1);

    for (int L = 0; L < DEPTH; L++) {
        // QKV: BN=128 2-buf (+XCD swizzle)
        gemm_kernel<0, 128><<<dim3(QKVN / 128, MTOT / 128, 1), 256, 0, stream>>>(
            hbuf, wqkv_t + (size_t)L * DIM * QKVN, nullptr, qkvb, nullptr, vtb,
            QKVN, DIM, DIM);
        attn_kernel<<<dim3(SEQ / 64, HEADS, BATCH), 256, 0, stream>>>(qkvb, vtb, aob);
        // proj: BN=128, split-K=2 (+XCD swizzle)
        gemm_kernel<2, 128><<<dim3(DIM / 128, MTOT / 128, 2), 256, 0, stream>>>(
            aob, wo_t + (size_t)L * DIM * DIM, nullptr, nullptr, Pp, nullptr,
            DIM, DIM, 384);
        lnr_kernel<<<MTOT, 192, 0, stream>>>(out, out, Pp, 2, b_o + L * DIM,
                                             ln2_w + L * DIM, ln2_b + L * DIM, hbuf, 1);
        // MLP1: BN=64 2-buf (within-run verified 48us) (+XCD swizzle)
        gemm_kernel<1, 64><<<dim3(MLPD / 64, MTOT / 128, 1), 256, 0, stream>>>(
            hbuf, w1_t + (size_t)L * DIM * MLPD, b1 + L * MLPD, midb, nullptr, nullptr,
            MLPD, DIM, DIM);
        // MLP2: BN=128, split-K=4 (+XCD swizzle)
        gemm_kernel<2, 128><<<dim3(DIM / 128, MTOT / 128, 4), 256, 0, stream>>>(
            midb, w2_t + (size_t)L * MLPD * DIM, nullptr, nullptr, Pm, nullptr,
            DIM, MLPD, 768);
        if (L < DEPTH - 1) {
            lnr_kernel<<<MTOT, 192, 0, stream>>>(out, out, Pm, 4, b2 + L * DIM,
                                                 ln1_w + (L + 1) * DIM,
                                                 ln1_b + (L + 1) * DIM, hbuf, 1);
        } else {
            lnr_kernel<<<MTOT, 192, 0, stream>>>(out, out, Pm, 4, b2 + L * DIM,
                                                 ln1_w, ln1_b, hbuf, 0);
        }
    }
}